// Round 2
// baseline (830.626 us; speedup 1.0000x reference)
//
#include <hip/hip_runtime.h>

#define NN 4096
#define BB 4

typedef __attribute__((ext_vector_type(8))) short short8;
typedef __attribute__((ext_vector_type(16))) float f32x16;

__device__ inline unsigned short f2bf(float f) {
    unsigned int u = __float_as_uint(f);
    u += 0x7fffu + ((u >> 16) & 1u);   // RNE; inputs finite
    return (unsigned short)(u >> 16);
}

// ---------------------------------------------------------------------------
// prep_z: Zt[i][b][f][k] = (X[b] @ w_i)^T in bf16, via MFMA 32x32x16.
// D = A*B with A = w^T (f x c, gathered by coalesced scalar loads, L2-hot),
// B = X^T (c x k, lane reads 8 consecutive fp32 of an X row = 2 float4).
// Grid: 256 blocks (b*64 + ktile64) x 256 thr; wave -> (ftile, ktile32).
// No LDS, no barriers; all loads independent -> batched, latency-tolerant.
// ---------------------------------------------------------------------------
__global__ __launch_bounds__(256) void prep_z(
    const float* __restrict__ X,
    const float* __restrict__ w0, const float* __restrict__ w1, const float* __restrict__ w2,
    unsigned short* __restrict__ Zt)
{
    const int blk = blockIdx.x;
    const int b = blk >> 6;
    const int k0 = (blk & 63) << 6;
    const int t = threadIdx.x, lane = t & 63, w = t >> 6;
    const int f0 = (w & 1) << 5;             // f-tile base (0 or 32)
    const int kw = k0 + ((w >> 1) << 5);     // wave's 32 k-cols
    const int l31 = lane & 31;
    const int lg = (lane >> 5) << 3;         // k-chunk sub-offset (0 or 8)

    // B-frags: X^T. B[c][n=k-col]: lane reads X[kw+l31][c*16+lg .. +8)
    short8 bx[4];
    const float* xp = X + ((size_t)b * NN + kw + l31) * 64 + lg;
    #pragma unroll
    for (int c = 0; c < 4; ++c) {
        float4 x0 = *(const float4*)(xp + c * 16);
        float4 x1 = *(const float4*)(xp + c * 16 + 4);
        bx[c][0] = (short)f2bf(x0.x); bx[c][1] = (short)f2bf(x0.y);
        bx[c][2] = (short)f2bf(x0.z); bx[c][3] = (short)f2bf(x0.w);
        bx[c][4] = (short)f2bf(x1.x); bx[c][5] = (short)f2bf(x1.y);
        bx[c][6] = (short)f2bf(x1.z); bx[c][7] = (short)f2bf(x1.w);
    }
    const float* ws_[3] = {w0, w1, w2};
    #pragma unroll
    for (int i = 0; i < 3; ++i) {
        const float* wp = ws_[i];
        f32x16 acc = {};
        #pragma unroll
        for (int c = 0; c < 4; ++c) {
            // A-frag: w^T[f][cc] = w[cc][f], f = f0+l31, cc = c*16+lg+j
            short8 aw;
            #pragma unroll
            for (int j = 0; j < 8; ++j)
                aw[j] = (short)f2bf(wp[(c * 16 + lg + j) * 64 + f0 + l31]);
            acc = __builtin_amdgcn_mfma_f32_32x32x16_bf16(aw, bx[c], acc, 0, 0, 0);
        }
        // store D[f][k]: row f = f0+(j&3)+8*(j>>2)+4*(lane>>5), col k = kw+l31
        unsigned short* zp = Zt + (((size_t)i * BB + b) * 64) * NN;
        #pragma unroll
        for (int j = 0; j < 16; ++j) {
            int f = f0 + (j & 3) + ((j >> 2) << 3) + ((lane >> 5) << 2);
            zp[(size_t)f * NN + kw + l31] = f2bf(acc[j]);
        }
    }
}

// ---------------------------------------------------------------------------
// gnn_main: out[b][m][f] = relu( sum_i A_i[b] @ Z_i[b] ).
// Grid: 512 blocks (b*128 + mtile32) x 256 thr (4 waves); wave w owns
// k-range [w*1024, (w+1)*1024). NO LDS / barriers in the K-loop: MFMA A/B
// fragments are loaded directly from global (A fp32 -> cvt bf16 in-register;
// fragment layout m=lane&31, k=(lane>>5)*8+j is 32B/16B contiguous per lane).
// Sum over the 3 A-matrices is fused into one accumulator pair per wave.
// 2 blocks/CU = 8 independent waves streaming ~24KB in flight each.
// Epilogue: one barrier, LDS reduce over the 4 k-quarter waves, relu, store.
// ---------------------------------------------------------------------------
__global__ __launch_bounds__(256, 2) void gnn_main(
    const float* __restrict__ A0, const float* __restrict__ A1, const float* __restrict__ A2,
    const unsigned short* __restrict__ Zt,
    float* __restrict__ out)
{
    __shared__ float red[4 * 32 * 64];       // 32 KB: per-wave partial C tiles
    const int blk = blockIdx.x;
    const int b = blk >> 7;
    const int m0 = (blk & 127) << 5;
    const int t = threadIdx.x;
    const int lane = t & 63;
    const int w = t >> 6;

    const int mrow = lane & 31;              // A-frag row / Zt row (n)
    const int kgrp = (lane >> 5) << 3;       // k sub-chunk (0 or 8)

    const size_t Aoff = (size_t)b * NN * NN + (size_t)(m0 + mrow) * NN + kgrp;
    const float* pA[3] = {A0 + Aoff, A1 + Aoff, A2 + Aoff};
    const unsigned short* pZ[3][2];
    #pragma unroll
    for (int i = 0; i < 3; ++i)
        #pragma unroll
        for (int nt = 0; nt < 2; ++nt)
            pZ[i][nt] = Zt + (((size_t)i * BB + b) * 64 + nt * 32 + mrow) * NN + kgrp;

    f32x16 acc0 = {}, acc1 = {};

    const int kbeg = w << 10;
    for (int k = kbeg; k < kbeg + 1024; k += 32) {
        float4 a[3][2][2];                   // [i][k16-half][float4 pair] fp32 A
        short8 zb[3][2][2];                  // [i][k16-half][n-tile]
        #pragma unroll
        for (int u = 0; u < 2; ++u) {
            const int kk = k + u * 16;
            #pragma unroll
            for (int i = 0; i < 3; ++i) {
                const float* ap = pA[i] + kk;
                a[i][u][0] = *(const float4*)ap;
                a[i][u][1] = *(const float4*)(ap + 4);
                zb[i][u][0] = *(const short8*)(pZ[i][0] + kk);
                zb[i][u][1] = *(const short8*)(pZ[i][1] + kk);
            }
        }
        #pragma unroll
        for (int u = 0; u < 2; ++u)
            #pragma unroll
            for (int i = 0; i < 3; ++i) {
                short8 af;
                af[0] = (short)f2bf(a[i][u][0].x); af[1] = (short)f2bf(a[i][u][0].y);
                af[2] = (short)f2bf(a[i][u][0].z); af[3] = (short)f2bf(a[i][u][0].w);
                af[4] = (short)f2bf(a[i][u][1].x); af[5] = (short)f2bf(a[i][u][1].y);
                af[6] = (short)f2bf(a[i][u][1].z); af[7] = (short)f2bf(a[i][u][1].w);
                acc0 = __builtin_amdgcn_mfma_f32_32x32x16_bf16(af, zb[i][u][0], acc0, 0, 0, 0);
                acc1 = __builtin_amdgcn_mfma_f32_32x32x16_bf16(af, zb[i][u][1], acc1, 0, 0, 0);
            }
    }

    // epilogue: C/D layout col=lane&31, row=(j&3)+8*(j>>2)+4*(lane>>5)
    float* myred = red + w * 2048;
    #pragma unroll
    for (int j = 0; j < 16; ++j) {
        int row = (j & 3) + ((j >> 2) << 3) + ((lane >> 5) << 2);
        myred[row * 64 + mrow] = acc0[j];          // banks: col%32, 2-way (free)
        myred[row * 64 + 32 + mrow] = acc1[j];
    }
    __syncthreads();
    float* obase = out + ((size_t)b * NN + m0) * 64;
    const int e = t * 8;
    #pragma unroll
    for (int p = 0; p < 2; ++p) {
        float4 s = {0.f, 0.f, 0.f, 0.f};
        #pragma unroll
        for (int ww = 0; ww < 4; ++ww) {
            float4 v = *(const float4*)(red + ww * 2048 + e + p * 4);
            s.x += v.x; s.y += v.y; s.z += v.z; s.w += v.w;
        }
        s.x = fmaxf(s.x, 0.f); s.y = fmaxf(s.y, 0.f);
        s.z = fmaxf(s.z, 0.f); s.w = fmaxf(s.w, 0.f);
        *(float4*)(obase + e + p * 4) = s;
    }
}

extern "C" void kernel_launch(void* const* d_in, const int* in_sizes, int n_in,
                              void* d_out, int out_size, void* d_ws, size_t ws_size,
                              hipStream_t stream) {
    const float* X  = (const float*)d_in[0];
    const float* A0 = (const float*)d_in[1];
    const float* A1 = (const float*)d_in[2];
    const float* A2 = (const float*)d_in[3];
    const float* w0 = (const float*)d_in[4];
    const float* w1 = (const float*)d_in[5];
    const float* w2 = (const float*)d_in[6];
    float* out = (float*)d_out;
    unsigned short* Zt = (unsigned short*)d_ws;  // 3*4*64*4096 bf16 = 6.3 MB

    prep_z<<<256, 256, 0, stream>>>(X, w0, w1, w2, Zt);
    gnn_main<<<512, 256, 0, stream>>>(A0, A1, A2, Zt, out);
}